// Round 1
// baseline (39.336 us; speedup 1.0000x reference)
//
#include <hip/hip_runtime.h>

// FlashRecoModel: waveform[b,p,t] = sum_f pe[b,f,p]*conf[b,f] * w[b,f,t]
// w = normalized Gaussian over ticks centered at clip(time*T, 0, T-1), sigma=1.
// Gaussian support truncated at |z| <= 8 (exp(-32) ~ 1.3e-14, far below threshold).
//
// One block per output row (b,p); LDS accumulator of T ticks; scatter via
// ds_add_f32 atomics; coalesced float4 row write.

#define FLASHES 128
#define TICKS   2048
#define WMAX    32          // max window length (17 for sigma=1)
#define BLOCK   256

__global__ __launch_bounds__(BLOCK) void flash_reco_kernel(
    const float* __restrict__ pe,      // [B, F, P]
    const float* __restrict__ ftime,   // [B, F]
    const float* __restrict__ fconf,   // [B, F]
    const int*   __restrict__ nticks_p,// scalar
    const float* __restrict__ sigma_p, // scalar
    float* __restrict__ out,           // [B, P, T]
    int P)
{
    __shared__ float acc[TICKS];
    __shared__ float wtab[FLASHES * WMAX];
    __shared__ float spe[FLASHES];
    __shared__ int   lo_s[FLASHES];
    __shared__ int   len_s[FLASHES];

    const int tid = threadIdx.x;
    const int b   = blockIdx.x / P;
    const int p   = blockIdx.x % P;
    const int nt  = *nticks_p;           // 2048
    const float sigma = *sigma_p;        // 1.0

    // zero the tick accumulator
    #pragma unroll
    for (int i = 0; i < TICKS / BLOCK; ++i)
        acc[i * BLOCK + tid] = 0.0f;

    // per-flash window + normalized weights (threads 0..F-1, one flash each)
    if (tid < FLASHES) {
        const float tm = ftime[b * FLASHES + tid];
        const float cf = fconf[b * FLASHES + tid];
        spe[tid] = pe[(b * FLASHES + tid) * P + p] * cf;

        float tb = tm * (float)nt;
        tb = fminf(fmaxf(tb, 0.0f), (float)(nt - 1));

        const float r = 8.0f * sigma;
        int lo = (int)ceilf(tb - r);
        if (lo < 0) lo = 0;
        int hi = (int)floorf(tb + r);
        if (hi > nt - 1)    hi = nt - 1;
        if (hi > TICKS - 1) hi = TICKS - 1;           // LDS safety
        if (hi - lo + 1 > WMAX) hi = lo + WMAX - 1;   // LDS safety
        const int len = hi - lo + 1;

        const float inv_sig = 1.0f / sigma;
        float sum = 0.0f;
        for (int k = 0; k < len; ++k) {
            const float z = ((float)(lo + k) - tb) * inv_sig;
            const float e = __expf(-0.5f * z * z);
            wtab[tid * WMAX + k] = e;
            sum += e;
        }
        const float inv = 1.0f / (sum + 1e-10f);
        for (int k = 0; k < len; ++k)
            wtab[tid * WMAX + k] *= inv;

        lo_s[tid]  = lo;
        len_s[tid] = len;
    }
    __syncthreads();

    // scatter: (flash, k) pairs -> LDS atomics. 128*32/256 = 16 iters.
    #pragma unroll
    for (int it = 0; it < (FLASHES * WMAX) / BLOCK; ++it) {
        const int idx = it * BLOCK + tid;
        const int f   = idx >> 5;    // WMAX = 32
        const int k   = idx & (WMAX - 1);
        if (k < len_s[f]) {
            atomicAdd(&acc[lo_s[f] + k], spe[f] * wtab[idx]);
        }
    }
    __syncthreads();

    // coalesced float4 write of row (b, p, :)
    float4* out4 = (float4*)(out + ((long)b * P + p) * TICKS);
    const float4* acc4 = (const float4*)acc;
    #pragma unroll
    for (int i = 0; i < TICKS / (BLOCK * 4); ++i)
        out4[i * BLOCK + tid] = acc4[i * BLOCK + tid];
}

extern "C" void kernel_launch(void* const* d_in, const int* in_sizes, int n_in,
                              void* d_out, int out_size, void* d_ws, size_t ws_size,
                              hipStream_t stream) {
    const float* pe     = (const float*)d_in[0];  // [B,F,P]
    const float* ftime  = (const float*)d_in[1];  // [B,F,1]
    const float* fconf  = (const float*)d_in[2];  // [B,F,1]
    const int*   nt     = (const int*)d_in[3];    // scalar
    const float* sigma  = (const float*)d_in[4];  // scalar

    const int BF = in_sizes[1];          // B*F = 1024
    const int P  = in_sizes[0] / BF;     // 256
    const int B  = BF / FLASHES;         // 8

    flash_reco_kernel<<<dim3(B * P), dim3(BLOCK), 0, stream>>>(
        pe, ftime, fconf, nt, sigma, (float*)d_out, P);
}

// Round 2
// 12.031 us; speedup vs baseline: 3.2696x; 3.2696x over previous
//
#include <hip/hip_runtime.h>

// FlashRecoModel: out[b,p,t] = sum_f pe[b,f,p]*conf[b,f] * w[b,f,t]
// w = Gaussian(center=clip(time*T,0,T-1), sigma) normalized over ticks.
// Tail beyond |z|=8 is exp(-32)~1.3e-14 -> truncated (threshold 1.8e-2).
//
// Tile-gather design: block = (b, 32-tick tile). Ballot-compacted list of
// flashes intersecting the tile (deterministic, no fp atomics); weights
// computed once per (b,f,tile); per-thread register accumulation over p;
// padded-LDS transpose; coalesced float4 writes.

#define FLASHES 128
#define WMAX    32     // max window length (17 for sigma=1)
#define TT      32     // ticks per tile
#define BLOCK   256    // == P
#define MAXSLOT 128    // worst case: all flashes in one tile

__global__ __launch_bounds__(BLOCK) void flash_reco_tile(
    const float* __restrict__ pe,      // [B, F, P]
    const float* __restrict__ ftime,   // [B, F]
    const float* __restrict__ fconf,   // [B, F]
    const float* __restrict__ sig_p,   // scalar
    float* __restrict__ out,           // [B, P, T]
    int P, int T, int ntiles)
{
    __shared__ int   wcnt[4];
    __shared__ int   fl_f [MAXSLOT];
    __shared__ float fl_tb[MAXSLOT];
    __shared__ float fl_cf[MAXSLOT];
    __shared__ int   fl_lo[MAXSLOT];
    __shared__ int   fl_len[MAXSLOT];
    __shared__ float dinv [MAXSLOT];
    __shared__ float wt   [MAXSLOT * TT];      // 16 KB, tile weights (unnormalized)
    __shared__ float stg  [BLOCK * (TT + 1)];  // 33 KB, padded transpose staging

    const int tid  = threadIdx.x;
    const int b    = blockIdx.x / ntiles;
    const int tile = blockIdx.x % ntiles;
    const int t0   = tile * TT;
    const float sigma   = *sig_p;
    const float inv_sig = 1.0f / sigma;

    // ---- phase 1: find flashes whose window intersects [t0, t0+TT) ----
    bool act = false;
    float tb = 0.f, cf = 0.f;
    int lo = 0, len = 0;
    if (tid < FLASHES) {
        const float tm = ftime[b * FLASHES + tid];
        cf = fconf[b * FLASHES + tid];
        tb = fminf(fmaxf(tm * (float)T, 0.0f), (float)(T - 1));
        const float r = 8.0f * sigma;
        lo = (int)ceilf(tb - r);  if (lo < 0) lo = 0;
        int hi = (int)floorf(tb + r);  if (hi > T - 1) hi = T - 1;
        if (hi - lo + 1 > WMAX) hi = lo + WMAX - 1;
        len = hi - lo + 1;
        act = (lo <= t0 + TT - 1) && (hi >= t0);
    }
    // deterministic compaction: ballot + per-wave prefix (waves 2,3 inactive)
    const unsigned long long m = __ballot(act);
    const int lane = tid & 63, wv = tid >> 6;
    if (lane == 0) wcnt[wv] = __popcll(m);
    __syncthreads();
    if (act) {
        const int slot = __popcll(m & ((1ULL << lane) - 1ULL))
                       + (wv == 1 ? wcnt[0] : 0);
        fl_f[slot]  = tid;
        fl_tb[slot] = tb;
        fl_cf[slot] = cf;
        fl_lo[slot] = lo;
        fl_len[slot] = len;
    }
    __syncthreads();
    const int count = wcnt[0] + wcnt[1];

    // ---- phase 2a: unnormalized tile weights, parallel over (slot, j) ----
    for (int idx = tid; idx < count * TT; idx += BLOCK) {
        const int a = idx >> 5, j = idx & (TT - 1);
        const float z = ((float)(t0 + j) - fl_tb[a]) * inv_sig;
        wt[idx] = __expf(-0.5f * z * z);
    }
    // ---- phase 2b: denominators (sum over full window), one thread/slot ----
    for (int a = tid; a < count; a += BLOCK) {
        const float tbv = fl_tb[a];
        const int lov = fl_lo[a], lenv = fl_len[a];
        float s = 0.0f;
        for (int k = 0; k < lenv; ++k) {
            const float z = ((float)(lov + k) - tbv) * inv_sig;
            s += __expf(-0.5f * z * z);
        }
        dinv[a] = 1.0f / (s + 1e-10f);
    }
    __syncthreads();

    // ---- phase 3: per-thread (p = tid) register accumulation ----
    float acc[TT];
    #pragma unroll
    for (int j = 0; j < TT; ++j) acc[j] = 0.0f;

    for (int a = 0; a < count; ++a) {
        const float s = pe[((long)b * FLASHES + fl_f[a]) * P + tid]  // coalesced
                      * fl_cf[a] * dinv[a];
        const float4* w4 = (const float4*)&wt[a * TT];   // uniform -> broadcast
        #pragma unroll
        for (int q = 0; q < TT / 4; ++q) {
            const float4 w = w4[q];
            acc[q*4+0] += s * w.x;
            acc[q*4+1] += s * w.y;
            acc[q*4+2] += s * w.z;
            acc[q*4+3] += s * w.w;
        }
    }

    // ---- phase 4: padded-LDS transpose, coalesced float4 writes ----
    #pragma unroll
    for (int j = 0; j < TT; ++j) stg[tid * (TT + 1) + j] = acc[j];  // 2-way (free)
    __syncthreads();

    const long rowbase = (long)b * P * T + t0;
    #pragma unroll
    for (int g = 0; g < BLOCK / 32; ++g) {
        const int p  = g * 32 + (tid >> 3);
        const int j4 = (tid & 7) * 4;
        float4 v;
        v.x = stg[p * (TT + 1) + j4 + 0];
        v.y = stg[p * (TT + 1) + j4 + 1];
        v.z = stg[p * (TT + 1) + j4 + 2];
        v.w = stg[p * (TT + 1) + j4 + 3];
        *(float4*)(out + rowbase + (long)p * T + j4) = v;
    }
}

extern "C" void kernel_launch(void* const* d_in, const int* in_sizes, int n_in,
                              void* d_out, int out_size, void* d_ws, size_t ws_size,
                              hipStream_t stream) {
    const float* pe    = (const float*)d_in[0];  // [B,F,P]
    const float* ftime = (const float*)d_in[1];  // [B,F,1]
    const float* fconf = (const float*)d_in[2];  // [B,F,1]
    const float* sigma = (const float*)d_in[4];  // scalar

    const int BF = in_sizes[1];            // B*F = 1024
    const int P  = in_sizes[0] / BF;       // 256
    const int B  = BF / FLASHES;           // 8
    const int T  = out_size / (B * P);     // 2048 (== *d_in[3])
    const int ntiles = (T + TT - 1) / TT;  // 64

    flash_reco_tile<<<dim3(B * ntiles), dim3(BLOCK), 0, stream>>>(
        pe, ftime, fconf, sigma, (float*)d_out, P, T, ntiles);
}